// Round 10
// baseline (311.528 us; speedup 1.0000x reference)
//
#include <hip/hip_runtime.h>
#include <hip/hip_bf16.h>

typedef __attribute__((ext_vector_type(8))) short bf16x8;
typedef __attribute__((ext_vector_type(4))) float f32x4;
typedef __attribute__((ext_vector_type(8))) unsigned short u16x8;
typedef __attribute__((ext_vector_type(2))) unsigned short u16x2;

__device__ __forceinline__ unsigned short f2bf(float f) {
  union { float f; unsigned u; } c; c.f = f;
  unsigned u = c.u;
  u = (u + 0x7FFFu + ((u >> 16) & 1u)) >> 16;   // RNE
  return (unsigned short)u;
}

__device__ __forceinline__ void gld_lds16(const void* g, void* l) {
  __builtin_amdgcn_global_load_lds(
      (__attribute__((address_space(1))) unsigned int*)g,
      (__attribute__((address_space(3))) unsigned int*)l,
      16, 0, 0);
}

// Raw workgroup barrier + compiler memory fence (no vmcnt/lgkm drain).
#define BAR() asm volatile("s_barrier" ::: "memory")

// ---------------- conversion kernel: K -> K16, V -> Vt only ----------------
// [0,2048): K->K16 (first 32 blocks also zero lsum) ; [2048,3072): V -> Vt.
__global__ void cvt_kv(const float* __restrict__ Kw, unsigned short* __restrict__ K16,
                       const float* __restrict__ V, unsigned short* __restrict__ Vt,
                       float* __restrict__ lsum) {
  const int b = blockIdx.x;
  const int tid = threadIdx.x;
  if (b < 32) lsum[b * 256 + tid] = 0.f;

  if (b < 2048) {
    const int i = (b * 256 + tid) * 8;
    const float4* p = (const float4*)(Kw + i);
    float4 a = p[0], bb = p[1];
    u16x8 r;
    r[0] = f2bf(a.x); r[1] = f2bf(a.y); r[2] = f2bf(a.z); r[3] = f2bf(a.w);
    r[4] = f2bf(bb.x); r[5] = f2bf(bb.y); r[6] = f2bf(bb.z); r[7] = f2bf(bb.w);
    *(u16x8*)(K16 + i) = r;
  } else {
    // 64x64 tile transpose, float4 reads, u16x8 stores.
    __shared__ unsigned short t[64][66];
    const int tile = b - 2048;
    const int p0 = (tile & 63) * 64;
    const int e0 = (tile >> 6) * 64;
    const int cg = (tid & 15) * 4;
    const int pr = tid >> 4;
#pragma unroll
    for (int i = 0; i < 4; ++i) {
      int p = pr + i * 16;
      float4 v = *(const float4*)(V + (size_t)(p0 + p) * 1024 + e0 + cg);
      u16x2 lo, hi;
      lo[0] = f2bf(v.x); lo[1] = f2bf(v.y);
      hi[0] = f2bf(v.z); hi[1] = f2bf(v.w);
      *(u16x2*)&t[p][cg] = lo;
      *(u16x2*)&t[p][cg + 2] = hi;
    }
    __syncthreads();
    const int op = (tid & 7) * 8;
    const int oe = tid >> 3;
#pragma unroll
    for (int h = 0; h < 2; ++h) {
      int e = oe + h * 32;
      u16x8 r;
#pragma unroll
      for (int i = 0; i < 8; ++i) r[i] = t[op + i][e];
      *(u16x8*)(Vt + (size_t)(e0 + e) * 4096 + p0 + op) = r;
    }
  }
}

// ---- 8-phase NT GEMM (R7 schedule). EPI==0: A is fp32 (x), converted ------
// in-registers during staging (kills the x16 round-trip). EPI==1: R7-exact.
// EPI==0: BM=256,BN=256, grid 512. P = exp2(scale*(Af32.B^T)) -> Pout + lsum.
// EPI==1: BM=128,BN=256, grid 256. C = (A.B^T) / lin[row] -> Cout fp32.
//
// EPI0 per K-tile g (4 phases):
//  p0: bF(8)+aF0 ds_reads | issue 8 global_load_dwordx4 of x for A(g+1)
//  p1: aF1 | stB(0,g+2)   p2: aF2 | stB(1,g+2)
//  p3: aF3 | BAR | MFMA | vmcnt(4) [drains A(g+1) regs + B(g+1) lds-loads,
//      leaves B(g+2) in flight] | cvt+4x ds_write_b128 A(g+1)->buf[(g+1)&1]
//      | lgkmcnt(0) | BAR
//  (p0..p2 keep the R7 form {reads | stage | BAR | MFMA | BAR}.)
// WAR: buf[(g+1)&1] A-region last read at tile g-1 (barrier-separated).
template <int EPI>
__global__ __launch_bounds__(512, 2) void gemm8p(
    const void* __restrict__ Ap, const unsigned short* __restrict__ B,
    unsigned short* __restrict__ Pout, float* __restrict__ lsum,
    float* __restrict__ Cout, const float* __restrict__ lin, float scale) {
  constexpr int BM = EPI ? 128 : 256;
  constexpr int Kd = EPI ? 4096 : 1024;
  constexpr int Nc = EPI ? 1024 : 4096;
  constexpr int NT = Kd / 64;             // 16 / 64 K-tiles (pow2)
  constexpr int AU = BM / 128;            // A 16KB units per tile (2 / 1)
  constexpr int NU = AU + 2;              // + 2 B units
  constexpr int M_rep = BM / 32;          // 8 / 4
  constexpr int PH = M_rep / 2;           // 4 / 2 phases per tile

  __shared__ __align__(16) char lds[2 * NU * 16384];   // 128 / 96 KB

  const int tid = threadIdx.x;
  const int lane = tid & 63;
  const int w = tid >> 6;
  const int wm = w >> 2;
  const int wn = w & 3;
  const int q = lane >> 4;
  const int ml = lane & 15;

  const int bid = blockIdx.x;
  const int wg = (bid & 7) * (EPI ? 32 : 64) + (bid >> 3);
  const int m_t = EPI ? (wg >> 2) : (wg >> 4);
  const int n_t = EPI ? (wg & 3) : (wg & 15);
  const int row0 = m_t * BM;
  const int col0 = n_t * 256;

  const int cr = tid >> 3;                 // 0..63
  const int ss = (tid & 7) ^ (cr & 7);     // swizzled global k-chunk
  char* ldsw = lds + w * 1024;

  const int ccB = (q ^ (ml & 7)) * 16;
  const int aOff = (EPI ? 0 : wm) * 16384 + ((EPI ? wm * 64 : 0) + ml) * 128 + ccB;
  const int bOff = (AU + (wn >> 1)) * 16384 + ((wn & 1) * 64 + ml) * 128 + ccB;

  f32x4 acc[M_rep][4] = {};

  const unsigned short* A16 = (const unsigned short*)Ap;   // EPI1
  const float* Af = (const float*)Ap;                      // EPI0

  auto stA1 = [&](int t, int buf) {   // EPI1 only (bf16 gload_lds)
    const unsigned short* s = A16 + (size_t)(row0 + cr) * Kd + t * 64 + ss * 8;
    char* d = ldsw + (buf * NU) * 16384;
    gld_lds16(s, d);
    gld_lds16(s + (size_t)64 * Kd, d + 8192);
  };
  auto stB = [&](int b, int t, int buf) {
    const unsigned short* s = B + (size_t)(col0 + b * 128 + cr) * Kd + t * 64 + ss * 8;
    char* d = ldsw + (buf * NU + AU + b) * 16384;
    gld_lds16(s, d);
    gld_lds16(s + (size_t)64 * Kd, d + 8192);
  };

  // EPI0 A reg-staging: thread covers 4 chunk-rows (unit u, half j):
  // global row = row0 + u*128 + j*64 + cr ; k-elems = t*64 + ss*8 (+4).
  const float* pAx[4];
  if constexpr (EPI == 0) {
#pragma unroll
    for (int u = 0; u < 2; ++u)
#pragma unroll
      for (int j = 0; j < 2; ++j)
        pAx[u * 2 + j] = Af + (size_t)(row0 + u * 128 + j * 64 + cr) * 1024 + ss * 8;
  }
  float4 aR[8];
  auto ldAx = [&](int t) {   // issue 8 fp32 loads for tile t
#pragma unroll
    for (int k = 0; k < 4; ++k) {
      aR[2 * k] = *(const float4*)(pAx[k] + t * 64);
      aR[2 * k + 1] = *(const float4*)(pAx[k] + t * 64 + 4);
    }
  };
  auto wrAx = [&](int buf) {  // cvt + ds_write into swizzled A units
#pragma unroll
    for (int k = 0; k < 4; ++k) {
      const int u = k >> 1, j = k & 1;
      u16x8 c;
      c[0] = f2bf(aR[2 * k].x); c[1] = f2bf(aR[2 * k].y);
      c[2] = f2bf(aR[2 * k].z); c[3] = f2bf(aR[2 * k].w);
      c[4] = f2bf(aR[2 * k + 1].x); c[5] = f2bf(aR[2 * k + 1].y);
      c[6] = f2bf(aR[2 * k + 1].z); c[7] = f2bf(aR[2 * k + 1].w);
      const int r = j * 64 + cr;   // row within unit
      *(u16x8*)(lds + (buf * NU + u) * 16384 + (r * 8 + (tid & 7)) * 16) = c;
    }
  };

  // ---------------- prologue ----------------
  if constexpr (EPI == 0) {
    ldAx(0);                                   // A(0) fp32 -> regs
    stB(0, 0, 0); stB(1, 0, 0);
    stB(0, 1, 1); stB(1, 1, 1);
    asm volatile("s_waitcnt vmcnt(8)" ::: "memory");   // A(0) landed
    wrAx(0);
    asm volatile("s_waitcnt vmcnt(4) lgkmcnt(0)" ::: "memory");  // B(0) landed
    BAR();
  } else {
    stA1(0, 0);
    stB(0, 0, 0); stB(1, 0, 0);
    stB(0, 1, 1); stB(1, 1, 1);
    asm volatile("s_waitcnt vmcnt(4)" ::: "memory");
    BAR();
  }

  for (int g = 0; g < NT; ++g) {
    const char* base = lds + (g & 1) * (NU * 16384);
    const int tA = (g + 1) & (NT - 1);
    const int bufA = (g + 1) & 1;
    const int tB = (g + 2) & (NT - 1);
    const int bufB = g & 1;

    bf16x8 bF[4][2];
#pragma unroll
    for (int ni = 0; ni < 4; ++ni)
#pragma unroll
      for (int ks = 0; ks < 2; ++ks)
        bF[ni][ks] = *(const bf16x8*)(base + (bOff ^ (ks * 64)) + ni * 2048);

#pragma unroll
    for (int p = 0; p < PH; ++p) {
      bf16x8 aF[2][2];
#pragma unroll
      for (int i = 0; i < 2; ++i)
#pragma unroll
        for (int ks = 0; ks < 2; ++ks)
          aF[i][ks] = *(const bf16x8*)(base + ((aOff ^ (ks * 64)) + (2 * p + i) * 2048));

      if constexpr (EPI == 0) {
        if (p == 0) ldAx(tA);                 // fp32 A(g+1) -> regs
        else if (p == 1) stB(0, tB, bufB);
        else if (p == 2) stB(1, tB, bufB);
      } else {
        if (p == 0) stA1(tA, bufA);
        else { stB(0, tB, bufB); stB(1, tB, bufB); }
      }

      BAR();
      __builtin_amdgcn_s_setprio(1);
#pragma unroll
      for (int ks = 0; ks < 2; ++ks)
#pragma unroll
        for (int i = 0; i < 2; ++i)
#pragma unroll
          for (int ni = 0; ni < 4; ++ni)
            acc[2 * p + i][ni] = __builtin_amdgcn_mfma_f32_16x16x32_bf16(
                aF[i][ks], bF[ni][ks], acc[2 * p + i][ni], 0, 0, 0);
      __builtin_amdgcn_s_setprio(0);
      if (p == PH - 1) {
        if constexpr (EPI == 0) {
          // drain A(g+1) regs + B(g+1) lds-loads; B(g+2) stays in flight
          asm volatile("s_waitcnt vmcnt(4)" ::: "memory");
          __builtin_amdgcn_sched_barrier(0);   // keep cvt block here, not hoisted
          wrAx(bufA);
          asm volatile("s_waitcnt lgkmcnt(0)" ::: "memory");
        } else {
          asm volatile("s_waitcnt vmcnt(4)" ::: "memory");
        }
      }
      BAR();
    }
  }

  if constexpr (EPI == 0) {
#pragma unroll
    for (int mi = 0; mi < M_rep; ++mi) {
#pragma unroll
      for (int j = 0; j < 4; ++j) {
        const int gr = row0 + wm * (BM / 2) + mi * 16 + q * 4 + j;
        float rsum = 0.f;
#pragma unroll
        for (int ni = 0; ni < 4; ++ni) {
          const int gc = col0 + wn * 64 + ni * 16 + ml;
          float pv = exp2f(acc[mi][ni][j] * scale);  // scale includes log2(e)
          rsum += pv;
          Pout[(size_t)gr * Nc + gc] = f2bf(pv);
        }
        rsum += __shfl_xor(rsum, 1);
        rsum += __shfl_xor(rsum, 2);
        rsum += __shfl_xor(rsum, 4);
        rsum += __shfl_xor(rsum, 8);
        if (ml == 0) atomicAdd(&lsum[gr], rsum);
      }
    }
  } else {
#pragma unroll
    for (int mi = 0; mi < M_rep; ++mi) {
#pragma unroll
      for (int j = 0; j < 4; ++j) {
        const int gr = row0 + wm * (BM / 2) + mi * 16 + q * 4 + j;
        const float rl = 1.0f / lin[gr];
#pragma unroll
        for (int ni = 0; ni < 4; ++ni) {
          const int gc = col0 + wn * 64 + ni * 16 + ml;
          Cout[(size_t)gr * Nc + gc] = acc[mi][ni][j] * rl;
        }
      }
    }
  }
}

extern "C" void kernel_launch(void* const* d_in, const int* in_sizes, int n_in,
                              void* d_out, int out_size, void* d_ws,
                              size_t ws_size, hipStream_t stream) {
  const float* x = (const float*)d_in[0];   // [8192,1024] fp32
  const float* Kw = (const float*)d_in[1];  // [4096,1024]
  const float* Vw = (const float*)d_in[2];  // [4096,1024]
  float* out = (float*)d_out;               // [8192,1024]
  char* ws = (char*)d_ws;

  unsigned short* K16  = (unsigned short*)(ws + (16u << 20));     //  8 MB
  unsigned short* V16t = (unsigned short*)(ws + (24u << 20));     //  8 MB
  float*          lsum = (float*)(ws + (32u << 20));              // 32 KB
  unsigned short* P16  = (unsigned short*)(ws + (33u << 20));     // 64 MB

  cvt_kv<<<3072, 256, 0, stream>>>(Kw, K16, Vw, V16t, lsum);

  // GEMM1: P = exp(x . K16^T / 32) (x fp32, converted in-kernel), sums->lsum.
  gemm8p<0><<<512, 512, 0, stream>>>(
      x, K16, P16, lsum, nullptr, nullptr,
      0.03125f * 1.44269504088896340736f);
  // GEMM2: out = (P16 . V16t^T) / lsum[row]
  gemm8p<1><<<256, 512, 0, stream>>>(
      P16, V16t, nullptr, nullptr, out, lsum, 0.f);
}